// Round 5
// baseline (4863.522 us; speedup 1.0000x reference)
//
#include <hip/hip_runtime.h>

// FPS: input [8, 65536, 3] f32 -> (idx [8,1024] as f32 values, sampled [8,1024,3] f32)
// concatenated flat in d_out.
//
// Latency-bound sequential argmax (1023 rounds). 8 WGs/batch, 1024 thr/WG,
// 8 points/thread in REGISTERS -> zero per-round HBM point reads.
// Per round: in-register distance update (uncontracted fp32, reference order
// -> bit-exact), 48-bit monotonic key (dist_bits<<16 | (65535-n): larger dist
// wins, ties -> smaller index = numpy argmax first-occurrence), key-only wave
// butterfly, winner lane -> LDS, ONE __syncthreads, wave0 key-only reduce of
// 16 wave candidates, winner lane DUAL-PUBLISHES a self-tagged record
// (3x 64-bit words, round tag in low 16 bits of each; parity double-buffered):
//   copy L: plain sc0 stores  -> lands in the writer XCD's L2 (fast, ~200cyc)
//   copy I: relaxed agent-scope atomic stores -> IF-visible (slow, always works)
// ALL waves poll the 8 records: sc0 loads of copy L first; any lane not
// seeing its tag after 64 spins switches permanently to agent-scope polls of
// copy I. Same-XCD placement (expected for blocks {b,b+8,..} under the %8
// round-robin) -> L2-speed sync; any other placement -> one-time timeout,
// then IF-speed sync (== R4 behavior). Correctness NEVER depends on
// placement: stale L2 lines can't show the wanted tag (tags strictly
// increase), and per-word self-tagging makes mixed-age words harmless.
// Slot reuse at t+2 is ordered by tag transitivity (see R4 analysis).

#define NB    8
#define NPTS  65536
#define NSAMP 1024
#define WPB   8      // workgroups per batch
#define TPB   1024   // threads per workgroup
#define PPT   8      // points per thread (WPB*TPB*PPT == NPTS)
#define RECQ  16     // 16 ull = 128 B per record line

typedef unsigned long long ull;

// 3x 8B loads from one 128B line, L1-bypass (sc0) -> reads the XCD L2.
__device__ __forceinline__ void ld3_sc0(const ull* p, ull& a, ull& b, ull& c) {
  asm volatile(
      "global_load_dwordx2 %0, %3, off sc0\n\t"
      "global_load_dwordx2 %1, %3, off offset:8 sc0\n\t"
      "global_load_dwordx2 %2, %3, off offset:16 sc0\n\t"
      "s_waitcnt vmcnt(0)"
      : "=&v"(a), "=&v"(b), "=&v"(c) : "v"(p) : "memory");
}

// 3x 8B stores to one 128B line, write-through to the XCD L2 (fire-and-forget).
__device__ __forceinline__ void st3_sc0(ull* p, ull a, ull b, ull c) {
  asm volatile(
      "global_store_dwordx2 %3, %0, off sc0\n\t"
      "global_store_dwordx2 %3, %1, off offset:8 sc0\n\t"
      "global_store_dwordx2 %3, %2, off offset:16 sc0"
      :: "v"(a), "v"(b), "v"(c), "v"(p) : "memory");
}

__global__ __launch_bounds__(TPB, 4)
void fps_kernel(const float* __restrict__ pts, float* __restrict__ out,
                ull* __restrict__ ws) {
  const int wg   = blockIdx.x;   // 0..63
  const int b    = wg & 7;       // batch; blocks {b, b+8, ...} usually one XCD
  const int w    = wg >> 3;      // wg within batch, 0..7
  const int tid  = threadIdx.x;
  const int lane = tid & 63;
  const int wave = tid >> 6;     // 0..15

  const float* p = pts + (size_t)b * NPTS * 3;

  float px[PPT], py[PPT], pz[PPT], md[PPT];
#pragma unroll
  for (int i = 0; i < PPT; ++i) {
    const int n = w * (TPB * PPT) + i * TPB + tid;
    px[i] = p[3 * n + 0];
    py[i] = p[3 * n + 1];
    pz[i] = p[3 * n + 2];
    md[i] = 1e10f;               // BIG, matches reference init
  }

  float cx = p[0], cy = p[1], cz = p[2];   // first pick is index 0

  // ws (ull): [0 .. 2048)    copy L (sc0/L2) : batch b at b*256, 2 par x 8 wg x 16
  //           [2048 .. 4096) copy I (agent/IF): same layout
  ull* baseL = ws + (size_t)b * (2 * WPB * RECQ);
  ull* baseI = ws + (size_t)NB * (2 * WPB * RECQ) + (size_t)b * (2 * WPB * RECQ);

  float* out_idx = out + (size_t)b * NSAMP;
  float* out_smp = out + (size_t)NB * NSAMP + (size_t)b * NSAMP * 3;

  if (w == 0 && tid == 0) {
    out_idx[0] = 0.0f;
    out_smp[0] = cx; out_smp[1] = cy; out_smp[2] = cz;
  }

  __shared__ unsigned red[16][5];  // per-wave {key_hi, key_lo, x, y, z}

  bool useIF = false;              // per-lane: fell back to IF polling
  int  spins = 0;

  for (int t = 0; t < NSAMP - 1; ++t) {
    // ---- local distance update + thread-local best ----
    float bv = -1.0f; int bn = 0; float bx = 0.f, by = 0.f, bz = 0.f;
#pragma unroll
    for (int i = 0; i < PPT; ++i) {
      const float dx = __fsub_rn(px[i], cx);
      const float dy = __fsub_rn(py[i], cy);
      const float dz = __fsub_rn(pz[i], cz);
      const float d  = __fadd_rn(__fadd_rn(__fmul_rn(dx, dx), __fmul_rn(dy, dy)),
                                 __fmul_rn(dz, dz));
      const float m = fminf(md[i], d);
      md[i] = m;
      if (m > bv) {  // strict > keeps earliest i (smallest n) on ties
        bv = m; bn = w * (TPB * PPT) + i * TPB + tid;
        bx = px[i]; by = py[i]; bz = pz[i];
      }
    }
    const ull key0 = ((ull)__float_as_uint(bv) << 16) | (ull)(65535 - bn);

    // ---- key-only wave butterfly; winner lane writes LDS ----
    ull kmax = key0;
#pragma unroll
    for (int s = 1; s < 64; s <<= 1) {
      const ull o = __shfl_xor(kmax, s, 64);
      if (o > kmax) kmax = o;
    }
    if (key0 == kmax) {          // exactly one lane per wave (keys unique)
      red[wave][0] = (unsigned)(key0 >> 32);
      red[wave][1] = (unsigned)key0;
      red[wave][2] = __float_as_uint(bx);
      red[wave][3] = __float_as_uint(by);
      red[wave][4] = __float_as_uint(bz);
    }
    __syncthreads();  // the ONLY barrier per round

    const ull tag = (ull)(unsigned)(t + 1);   // 1..1023; 0xAAAA poison never matches
    const int par = t & 1;
    const size_t slot = (size_t)(par * WPB + w) * RECQ;

    if (wave == 0) {
      // key-only 16-candidate reduce; winner lane dual-publishes
      const int e = lane & 15;
      const ull k2 = ((ull)red[e][0] << 32) | (ull)red[e][1];
      ull k2max = k2;
#pragma unroll
      for (int s = 1; s < 16; s <<= 1) {
        const ull o = __shfl_xor(k2max, s, 64);
        if (o > k2max) k2max = o;
      }
      if (k2 == k2max && lane < 16) {   // exactly one publishing lane
        const unsigned xb = red[e][2];
        const unsigned yb = red[e][3];
        const unsigned zb = red[e][4];
        const ull w0 = (k2 << 16) | tag;
        const ull w1 = ((ull)xb << 32) | ((ull)(yb >> 16) << 16) | tag;
        const ull w2 = ((ull)(yb & 0xFFFFu) << 48) | ((ull)zb << 16) | tag;
        st3_sc0(baseL + slot, w0, w1, w2);           // fast copy (writer's L2)
        ull* recI = baseI + slot;                    // slow copy (IF-visible)
        __hip_atomic_store(recI + 0, w0, __ATOMIC_RELAXED, __HIP_MEMORY_SCOPE_AGENT);
        __hip_atomic_store(recI + 1, w1, __ATOMIC_RELAXED, __HIP_MEMORY_SCOPE_AGENT);
        __hip_atomic_store(recI + 2, w2, __ATOMIC_RELAXED, __HIP_MEMORY_SCOPE_AGENT);
      }
    }

    // ---- ALL waves poll; every lane loads record lane&7 ----
    ull r0 = 0, r1 = 0, r2 = 0;
    {
      const size_t roff = (size_t)(par * WPB + (lane & 7)) * RECQ;
      const ull* recL = baseL + roff;
      const ull* recI = baseI + roff;
      bool done = false;
      for (;;) {
        if (!done) {
          if (!useIF) {
            ld3_sc0(recL, r0, r1, r2);
          } else {
            r0 = __hip_atomic_load(recI + 0, __ATOMIC_RELAXED, __HIP_MEMORY_SCOPE_AGENT);
            r1 = __hip_atomic_load(recI + 1, __ATOMIC_RELAXED, __HIP_MEMORY_SCOPE_AGENT);
            r2 = __hip_atomic_load(recI + 2, __ATOMIC_RELAXED, __HIP_MEMORY_SCOPE_AGENT);
          }
          done = ((r0 & 0xFFFFull) == tag) & ((r1 & 0xFFFFull) == tag) &
                 ((r2 & 0xFFFFull) == tag);
          if (!done && !useIF && ++spins > 64) useIF = true;  // cross-XCD fallback
        }
        if (__all(done)) break;
        if (useIF) __builtin_amdgcn_s_sleep(1);
      }
      if (!useIF) spins = 0;
    }

    // ---- decode + xor-8 butterfly with full carry: every lane gets winner ----
    {
      ull   kk = r0 >> 16;
      float xx = __uint_as_float((unsigned)(r1 >> 32));
      float yy = __uint_as_float(((unsigned)((r1 >> 16) & 0xFFFFull) << 16) |
                                 (unsigned)(r2 >> 48));
      float zz = __uint_as_float((unsigned)((r2 >> 16) & 0xFFFFFFFFull));
#pragma unroll
      for (int s = 1; s < 8; s <<= 1) {
        const ull   okey = __shfl_xor(kk, s, 64);
        const float ox   = __shfl_xor(xx, s, 64);
        const float oy   = __shfl_xor(yy, s, 64);
        const float oz   = __shfl_xor(zz, s, 64);
        if (okey > kk) { kk = okey; xx = ox; yy = oy; zz = oz; }
      }
      if (w == 0 && wave == 0 && lane == 0) {
        const int n2 = 65535 - (int)(kk & 0xFFFFull);
        out_idx[t + 1] = (float)n2;           // exact in fp32
        out_smp[(t + 1) * 3 + 0] = xx;
        out_smp[(t + 1) * 3 + 1] = yy;
        out_smp[(t + 1) * 3 + 2] = zz;
      }
      cx = xx; cy = yy; cz = zz;
    }
  }
}

extern "C" void kernel_launch(void* const* d_in, const int* in_sizes, int n_in,
                              void* d_out, int out_size, void* d_ws, size_t ws_size,
                              hipStream_t stream) {
  (void)in_sizes; (void)n_in; (void)out_size; (void)ws_size;
  const float* pts = (const float*)d_in[0];
  float* out = (float*)d_out;
  ull* ws = (ull*)d_ws;
  fps_kernel<<<dim3(NB * WPB), dim3(TPB), 0, stream>>>(pts, out, ws);
}

// Round 6
// 2714.113 us; speedup vs baseline: 1.7919x; 1.7919x over previous
//
#include <hip/hip_runtime.h>

// FPS: input [8, 65536, 3] f32 -> (idx [8,1024] as f32 values, sampled [8,1024,3] f32)
// concatenated flat in d_out.
//
// Latency-bound sequential argmax (1023 rounds). 8 WGs/batch (CONTIGUOUS
// blocks 8b..8b+7 -> same XCD if placement is chunked), 1024 thr/WG,
// 8 points/thread in REGISTERS. Per round:
//   - distance update (uncontracted fp32, reference order -> bit-exact),
//     48-bit monotonic key (dist_bits<<16 | (65535-n)): larger dist wins,
//     ties -> smaller index (numpy argmax first-occurrence)
//   - key-only wave butterfly; winner lane -> LDS; barrier1
//   - wave0: key-only reduce of 16 wave candidates; winner lane DUAL-PUBLISHES
//     self-tagged record (3x 8B words, round tag in low 16 bits of each;
//     parity double-buffered): copy L via sc0 stores (writer XCD's L2),
//     copy I via relaxed agent-scope atomics (IF, always visible)
//   - wave0 lanes 0..7 poll copy L with sc0 loads; a lane that fails 256
//     polls falls back PERMANENTLY to agent-scope polls of copy I (placement-
//     independent correctness; stale L2 lines can't fake a future tag, and
//     per-8B-word self-tags make mixed-age words harmless)
//   - wave0: decode + xor-8 full-carry butterfly -> winner; lane0 writes LDS
//     bc[] (+ d_out if w==0); barrier2; all threads read new centroid.
// Only 64 lanes/batch poll (R2-proven: cheaper than all-wave polling, R4/R5).
// Slot reuse at t+2 ordered by tag transitivity through barrier2.

#define NB    8
#define NPTS  65536
#define NSAMP 1024
#define WPB   8      // workgroups per batch
#define TPB   1024   // threads per workgroup
#define PPT   8      // points per thread (WPB*TPB*PPT == NPTS)
#define RECQ  16     // 16 ull = 128 B per record line

typedef unsigned long long ull;

// 3x 8B loads from one 128B line, L1-bypass (sc0) -> reads the XCD L2.
__device__ __forceinline__ void ld3_sc0(const ull* p, ull& a, ull& b, ull& c) {
  asm volatile(
      "global_load_dwordx2 %0, %3, off sc0\n\t"
      "global_load_dwordx2 %1, %3, off offset:8 sc0\n\t"
      "global_load_dwordx2 %2, %3, off offset:16 sc0\n\t"
      "s_waitcnt vmcnt(0)"
      : "=&v"(a), "=&v"(b), "=&v"(c) : "v"(p) : "memory");
}

// 3x 8B stores to one 128B line (vector L1 is write-through on CDNA: lands in L2).
__device__ __forceinline__ void st3_sc0(ull* p, ull a, ull b, ull c) {
  asm volatile(
      "global_store_dwordx2 %3, %0, off sc0\n\t"
      "global_store_dwordx2 %3, %1, off offset:8 sc0\n\t"
      "global_store_dwordx2 %3, %2, off offset:16 sc0"
      :: "v"(a), "v"(b), "v"(c), "v"(p) : "memory");
}

__global__ __launch_bounds__(TPB, 4)
void fps_kernel(const float* __restrict__ pts, float* __restrict__ out,
                ull* __restrict__ ws) {
  const int wg   = blockIdx.x;   // 0..63
  const int b    = wg >> 3;      // batch: CONTIGUOUS blocks 8b..8b+7
  const int w    = wg & 7;       // wg within batch, 0..7
  const int tid  = threadIdx.x;
  const int lane = tid & 63;
  const int wave = tid >> 6;     // 0..15

  const float* p = pts + (size_t)b * NPTS * 3;

  float px[PPT], py[PPT], pz[PPT], md[PPT];
#pragma unroll
  for (int i = 0; i < PPT; ++i) {
    const int n = w * (TPB * PPT) + i * TPB + tid;
    px[i] = p[3 * n + 0];
    py[i] = p[3 * n + 1];
    pz[i] = p[3 * n + 2];
    md[i] = 1e10f;               // BIG, matches reference init
  }

  float cx = p[0], cy = p[1], cz = p[2];   // first pick is index 0

  // ws (ull): [0 .. 2048)    copy L (sc0/L2): batch b at b*256, 2 par x 8 wg x 16
  //           [2048 .. 4096) copy I (agent/IF): same layout
  ull* baseL = ws + (size_t)b * (2 * WPB * RECQ);
  ull* baseI = ws + (size_t)NB * (2 * WPB * RECQ) + (size_t)b * (2 * WPB * RECQ);

  float* out_idx = out + (size_t)b * NSAMP;
  float* out_smp = out + (size_t)NB * NSAMP + (size_t)b * NSAMP * 3;

  if (w == 0 && tid == 0) {
    out_idx[0] = 0.0f;
    out_smp[0] = cx; out_smp[1] = cy; out_smp[2] = cz;
  }

  __shared__ unsigned red[16][5];  // per-wave {key_hi, key_lo, x, y, z}
  __shared__ float bc[3];          // winner xyz broadcast

  bool useIF = false;              // per-lane permanent fallback to IF polling

  for (int t = 0; t < NSAMP - 1; ++t) {
    // ---- local distance update + thread-local best ----
    float bv = -1.0f; int bn = 0; float bx = 0.f, by = 0.f, bz = 0.f;
#pragma unroll
    for (int i = 0; i < PPT; ++i) {
      const float dx = __fsub_rn(px[i], cx);
      const float dy = __fsub_rn(py[i], cy);
      const float dz = __fsub_rn(pz[i], cz);
      const float d  = __fadd_rn(__fadd_rn(__fmul_rn(dx, dx), __fmul_rn(dy, dy)),
                                 __fmul_rn(dz, dz));
      const float m = fminf(md[i], d);
      md[i] = m;
      if (m > bv) {  // strict > keeps earliest i (smallest n) on ties
        bv = m; bn = w * (TPB * PPT) + i * TPB + tid;
        bx = px[i]; by = py[i]; bz = pz[i];
      }
    }
    const ull key0 = ((ull)__float_as_uint(bv) << 16) | (ull)(65535 - bn);

    // ---- key-only wave butterfly; winner lane writes LDS ----
    ull kmax = key0;
#pragma unroll
    for (int s = 1; s < 64; s <<= 1) {
      const ull o = __shfl_xor(kmax, s, 64);
      if (o > kmax) kmax = o;
    }
    if (key0 == kmax) {          // exactly one lane per wave (keys unique)
      red[wave][0] = (unsigned)(key0 >> 32);
      red[wave][1] = (unsigned)key0;
      red[wave][2] = __float_as_uint(bx);
      red[wave][3] = __float_as_uint(by);
      red[wave][4] = __float_as_uint(bz);
    }
    __syncthreads();  // barrier1

    const ull tag = (ull)(unsigned)(t + 1);   // 1..1023; 0xAAAA poison never matches
    const int par = t & 1;

    if (wave == 0) {
      // ---- key-only 16-candidate reduce; winner lane dual-publishes ----
      const int e = lane & 15;
      const ull k2 = ((ull)red[e][0] << 32) | (ull)red[e][1];
      ull k2max = k2;
#pragma unroll
      for (int s = 1; s < 16; s <<= 1) {
        const ull o = __shfl_xor(k2max, s, 64);
        if (o > k2max) k2max = o;
      }
      if (k2 == k2max && lane < 16) {   // exactly one publishing lane
        const unsigned xb = red[e][2];
        const unsigned yb = red[e][3];
        const unsigned zb = red[e][4];
        const ull w0 = (k2 << 16) | tag;
        const ull w1 = ((ull)xb << 32) | ((ull)(yb >> 16) << 16) | tag;
        const ull w2 = ((ull)(yb & 0xFFFFu) << 48) | ((ull)zb << 16) | tag;
        const size_t slot = (size_t)(par * WPB + w) * RECQ;
        st3_sc0(baseL + slot, w0, w1, w2);           // fast copy first (L2)
        ull* recI = baseI + slot;                    // slow copy (IF-visible)
        __hip_atomic_store(recI + 0, w0, __ATOMIC_RELAXED, __HIP_MEMORY_SCOPE_AGENT);
        __hip_atomic_store(recI + 1, w1, __ATOMIC_RELAXED, __HIP_MEMORY_SCOPE_AGENT);
        __hip_atomic_store(recI + 2, w2, __ATOMIC_RELAXED, __HIP_MEMORY_SCOPE_AGENT);
      }

      // ---- lanes 0..7 poll (L2 copy, timeout -> IF copy) ----
      const size_t roff = (size_t)(par * WPB + (lane & 7)) * RECQ;
      const ull* recL = baseL + roff;
      const ull* recI = baseI + roff;
      const bool mine = (lane < WPB);
      bool done = !mine;
      ull r0 = 0, r1 = 0, r2 = 0;
      int spins = 0;
      for (;;) {
        if (!done) {
          if (!useIF) {
            ld3_sc0(recL, r0, r1, r2);
          } else {
            r0 = __hip_atomic_load(recI + 0, __ATOMIC_RELAXED, __HIP_MEMORY_SCOPE_AGENT);
            r1 = __hip_atomic_load(recI + 1, __ATOMIC_RELAXED, __HIP_MEMORY_SCOPE_AGENT);
            r2 = __hip_atomic_load(recI + 2, __ATOMIC_RELAXED, __HIP_MEMORY_SCOPE_AGENT);
          }
          done = ((r0 & 0xFFFFull) == tag) & ((r1 & 0xFFFFull) == tag) &
                 ((r2 & 0xFFFFull) == tag);
          if (!done && !useIF && ++spins > 256) useIF = true;  // cross-XCD fallback
        }
        if (__all(done)) break;
        if (useIF) __builtin_amdgcn_s_sleep(1);
      }

      // ---- decode + xor-8 full-carry butterfly (group 0 holds real data) ----
      ull   kk = r0 >> 16;
      float xx = __uint_as_float((unsigned)(r1 >> 32));
      float yy = __uint_as_float(((unsigned)((r1 >> 16) & 0xFFFFull) << 16) |
                                 (unsigned)(r2 >> 48));
      float zz = __uint_as_float((unsigned)((r2 >> 16) & 0xFFFFFFFFull));
#pragma unroll
      for (int s = 1; s < 8; s <<= 1) {
        const ull   okey = __shfl_xor(kk, s, 64);
        const float ox   = __shfl_xor(xx, s, 64);
        const float oy   = __shfl_xor(yy, s, 64);
        const float oz   = __shfl_xor(zz, s, 64);
        if (okey > kk) { kk = okey; xx = ox; yy = oy; zz = oz; }
      }
      if (lane == 0) {
        bc[0] = xx; bc[1] = yy; bc[2] = zz;
        if (w == 0) {
          const int n2 = 65535 - (int)(kk & 0xFFFFull);
          out_idx[t + 1] = (float)n2;           // exact in fp32
          out_smp[(t + 1) * 3 + 0] = xx;
          out_smp[(t + 1) * 3 + 1] = yy;
          out_smp[(t + 1) * 3 + 2] = zz;
        }
      }
    }
    __syncthreads();  // barrier2
    cx = bc[0]; cy = bc[1]; cz = bc[2];
  }
}

extern "C" void kernel_launch(void* const* d_in, const int* in_sizes, int n_in,
                              void* d_out, int out_size, void* d_ws, size_t ws_size,
                              hipStream_t stream) {
  (void)in_sizes; (void)n_in; (void)out_size; (void)ws_size;
  const float* pts = (const float*)d_in[0];
  float* out = (float*)d_out;
  ull* ws = (ull*)d_ws;
  fps_kernel<<<dim3(NB * WPB), dim3(TPB), 0, stream>>>(pts, out, ws);
}

// Round 7
// 2658.518 us; speedup vs baseline: 1.8294x; 1.0209x over previous
//
#include <hip/hip_runtime.h>

// FPS: input [8, 65536, 3] f32 -> (idx [8,1024] as f32 values, sampled [8,1024,3] f32)
// concatenated flat in d_out.
//
// Latency-bound sequential argmax (1023 rounds). 8 WGs/batch (CONTIGUOUS
// blocks 8b..8b+7 -> same XCD, verified by R6's 27% win), 1024 thr/WG,
// 8 points/thread in REGISTERS. Per round:
//   - distance update (uncontracted fp32, reference order -> bit-exact),
//     48-bit monotonic key (dist_bits<<16 | (65535-n)): larger dist wins,
//     ties -> smaller index (numpy argmax first-occurrence)
//   - key-only wave butterfly; winner lane -> LDS; barrier1
//   - wave0: key-only reduce of 16 wave candidates; winner lane publishes
//     self-tagged record (3x 8B words, round tag in low 16 bits of each;
//     parity double-buffered) via sc0 stores -> writer XCD's L2 (copy L).
//   - wave1 (R7): re-derives the same winner from red[] and mirrors the
//     record to copy I with relaxed agent-scope atomics (IF-visible).
//     Moving the mirror off wave0 removes the ~700cyc IF store-ack from
//     wave0's poll s_waitcnt vmcnt(0) (vmcnt counts the wave's own stores).
//   - wave0 lanes 0..7 poll copy L with sc0 loads; a lane that fails 256
//     polls falls back PERMANENTLY to agent-scope polls of copy I
//     (placement-independent correctness; stale L2 lines can't fake a
//     future tag; per-8B-word self-tags make mixed-age words harmless)
//   - key-only xor-8 butterfly -> winner key; owner WG = n2>>13 (WG w owns
//     indices [w*8192,(w+1)*8192)); lane0 shfl's xyz from lane src_wg,
//     writes LDS bc[] (+ d_out if w==0); barrier2; all read new centroid.
// Slot reuse at t+2 ordered by tag transitivity through barrier2.

#define NB    8
#define NPTS  65536
#define NSAMP 1024
#define WPB   8      // workgroups per batch
#define TPB   1024   // threads per workgroup
#define PPT   8      // points per thread (WPB*TPB*PPT == NPTS)
#define RECQ  16     // 16 ull = 128 B per record line

typedef unsigned long long ull;

// 3x 8B loads from one 128B line, L1-bypass (sc0) -> reads the XCD L2.
__device__ __forceinline__ void ld3_sc0(const ull* p, ull& a, ull& b, ull& c) {
  asm volatile(
      "global_load_dwordx2 %0, %3, off sc0\n\t"
      "global_load_dwordx2 %1, %3, off offset:8 sc0\n\t"
      "global_load_dwordx2 %2, %3, off offset:16 sc0\n\t"
      "s_waitcnt vmcnt(0)"
      : "=&v"(a), "=&v"(b), "=&v"(c) : "v"(p) : "memory");
}

// 3x 8B stores to one 128B line, fire-and-forget (vector L1 write-through -> L2).
__device__ __forceinline__ void st3_sc0(ull* p, ull a, ull b, ull c) {
  asm volatile(
      "global_store_dwordx2 %3, %0, off sc0\n\t"
      "global_store_dwordx2 %3, %1, off offset:8 sc0\n\t"
      "global_store_dwordx2 %3, %2, off offset:16 sc0"
      :: "v"(a), "v"(b), "v"(c), "v"(p) : "memory");
}

__global__ __launch_bounds__(TPB, 4)
void fps_kernel(const float* __restrict__ pts, float* __restrict__ out,
                ull* __restrict__ ws) {
  const int wg   = blockIdx.x;   // 0..63
  const int b    = wg >> 3;      // batch: CONTIGUOUS blocks 8b..8b+7 (one XCD)
  const int w    = wg & 7;       // wg within batch, 0..7
  const int tid  = threadIdx.x;
  const int lane = tid & 63;
  const int wave = tid >> 6;     // 0..15

  const float* p = pts + (size_t)b * NPTS * 3;

  float px[PPT], py[PPT], pz[PPT], md[PPT];
#pragma unroll
  for (int i = 0; i < PPT; ++i) {
    const int n = w * (TPB * PPT) + i * TPB + tid;
    px[i] = p[3 * n + 0];
    py[i] = p[3 * n + 1];
    pz[i] = p[3 * n + 2];
    md[i] = 1e10f;               // BIG, matches reference init
  }

  float cx = p[0], cy = p[1], cz = p[2];   // first pick is index 0

  // ws (ull): [0 .. 2048)    copy L (sc0/L2): batch b at b*256, 2 par x 8 wg x 16
  //           [2048 .. 4096) copy I (agent/IF): same layout
  ull* baseL = ws + (size_t)b * (2 * WPB * RECQ);
  ull* baseI = ws + (size_t)NB * (2 * WPB * RECQ) + (size_t)b * (2 * WPB * RECQ);

  float* out_idx = out + (size_t)b * NSAMP;
  float* out_smp = out + (size_t)NB * NSAMP + (size_t)b * NSAMP * 3;

  if (w == 0 && tid == 0) {
    out_idx[0] = 0.0f;
    out_smp[0] = cx; out_smp[1] = cy; out_smp[2] = cz;
  }

  __shared__ unsigned red[16][5];  // per-wave {key_hi, key_lo, x, y, z}
  __shared__ float bc[3];          // winner xyz broadcast

  bool useIF = false;              // per-lane permanent fallback to IF polling

  for (int t = 0; t < NSAMP - 1; ++t) {
    // ---- local distance update + thread-local best ----
    float bv = -1.0f; int bn = 0; float bx = 0.f, by = 0.f, bz = 0.f;
#pragma unroll
    for (int i = 0; i < PPT; ++i) {
      const float dx = __fsub_rn(px[i], cx);
      const float dy = __fsub_rn(py[i], cy);
      const float dz = __fsub_rn(pz[i], cz);
      const float d  = __fadd_rn(__fadd_rn(__fmul_rn(dx, dx), __fmul_rn(dy, dy)),
                                 __fmul_rn(dz, dz));
      const float m = fminf(md[i], d);
      md[i] = m;
      if (m > bv) {  // strict > keeps earliest i (smallest n) on ties
        bv = m; bn = w * (TPB * PPT) + i * TPB + tid;
        bx = px[i]; by = py[i]; bz = pz[i];
      }
    }
    const ull key0 = ((ull)__float_as_uint(bv) << 16) | (ull)(65535 - bn);

    // ---- key-only wave butterfly; winner lane writes LDS ----
    ull kmax = key0;
#pragma unroll
    for (int s = 1; s < 64; s <<= 1) {
      const ull o = __shfl_xor(kmax, s, 64);
      if (o > kmax) kmax = o;
    }
    if (key0 == kmax) {          // exactly one lane per wave (keys unique)
      red[wave][0] = (unsigned)(key0 >> 32);
      red[wave][1] = (unsigned)key0;
      red[wave][2] = __float_as_uint(bx);
      red[wave][3] = __float_as_uint(by);
      red[wave][4] = __float_as_uint(bz);
    }
    __syncthreads();  // barrier1

    const ull tag = (ull)(unsigned)(t + 1);   // 1..1023; 0xAAAA poison never matches
    const int par = t & 1;

    if (wave == 0) {
      // ---- key-only 16-candidate reduce; winner lane publishes copy L ----
      const int e = lane & 15;
      const ull k2 = ((ull)red[e][0] << 32) | (ull)red[e][1];
      ull k2max = k2;
#pragma unroll
      for (int s = 1; s < 16; s <<= 1) {
        const ull o = __shfl_xor(k2max, s, 64);
        if (o > k2max) k2max = o;
      }
      if (k2 == k2max && lane < 16) {   // exactly one publishing lane
        const unsigned xb = red[e][2];
        const unsigned yb = red[e][3];
        const unsigned zb = red[e][4];
        const ull w0 = (k2 << 16) | tag;
        const ull w1 = ((ull)xb << 32) | ((ull)(yb >> 16) << 16) | tag;
        const ull w2 = ((ull)(yb & 0xFFFFu) << 48) | ((ull)zb << 16) | tag;
        st3_sc0(baseL + (size_t)(par * WPB + w) * RECQ, w0, w1, w2);
      }

      // ---- lanes 0..7 poll (L2 copy, 256-spin timeout -> IF copy) ----
      const size_t roff = (size_t)(par * WPB + (lane & 7)) * RECQ;
      const ull* recL = baseL + roff;
      const ull* recI = baseI + roff;
      const bool mine = (lane < WPB);
      bool done = !mine;
      ull r0 = 0, r1 = 0, r2 = 0;
      int spins = 0;
      for (;;) {
        if (!done) {
          if (!useIF) {
            ld3_sc0(recL, r0, r1, r2);
          } else {
            r0 = __hip_atomic_load(recI + 0, __ATOMIC_RELAXED, __HIP_MEMORY_SCOPE_AGENT);
            r1 = __hip_atomic_load(recI + 1, __ATOMIC_RELAXED, __HIP_MEMORY_SCOPE_AGENT);
            r2 = __hip_atomic_load(recI + 2, __ATOMIC_RELAXED, __HIP_MEMORY_SCOPE_AGENT);
          }
          done = ((r0 & 0xFFFFull) == tag) & ((r1 & 0xFFFFull) == tag) &
                 ((r2 & 0xFFFFull) == tag);
          if (!done && !useIF && ++spins > 256) useIF = true;  // cross-XCD fallback
        }
        if (__all(done)) break;
        if (useIF) __builtin_amdgcn_s_sleep(1);
      }

      // ---- key-only xor-8 butterfly, then fetch xyz from owner lane ----
      ull kk = r0 >> 16;
#pragma unroll
      for (int s = 1; s < 8; s <<= 1) {
        const ull o = __shfl_xor(kk, s, 64);
        if (o > kk) kk = o;
      }
      // decode this lane's own record payload (only lanes 0..7 meaningful)
      const float xx = __uint_as_float((unsigned)(r1 >> 32));
      const float yy = __uint_as_float(((unsigned)((r1 >> 16) & 0xFFFFull) << 16) |
                                       (unsigned)(r2 >> 48));
      const float zz = __uint_as_float((unsigned)((r2 >> 16) & 0xFFFFFFFFull));
      const int n2  = 65535 - (int)(kk & 0xFFFFull);
      const int src = n2 >> 13;            // owner WG == source lane (0..7)
      const float wx = __shfl(xx, src, 64);
      const float wy = __shfl(yy, src, 64);
      const float wz = __shfl(zz, src, 64);
      if (lane == 0) {
        bc[0] = wx; bc[1] = wy; bc[2] = wz;
        if (w == 0) {
          out_idx[t + 1] = (float)n2;           // exact in fp32
          out_smp[(t + 1) * 3 + 0] = wx;
          out_smp[(t + 1) * 3 + 1] = wy;
          out_smp[(t + 1) * 3 + 2] = wz;
        }
      }
    } else if (wave == 1) {
      // ---- mirror publish to copy I (IF), entirely off wave0's path ----
      const int e = lane & 15;
      const ull k2 = ((ull)red[e][0] << 32) | (ull)red[e][1];
      ull k2max = k2;
#pragma unroll
      for (int s = 1; s < 16; s <<= 1) {
        const ull o = __shfl_xor(k2max, s, 64);
        if (o > k2max) k2max = o;
      }
      if (k2 == k2max && lane < 16) {
        const unsigned xb = red[e][2];
        const unsigned yb = red[e][3];
        const unsigned zb = red[e][4];
        const ull w0 = (k2 << 16) | tag;
        const ull w1 = ((ull)xb << 32) | ((ull)(yb >> 16) << 16) | tag;
        const ull w2 = ((ull)(yb & 0xFFFFu) << 48) | ((ull)zb << 16) | tag;
        ull* recI = baseI + (size_t)(par * WPB + w) * RECQ;
        __hip_atomic_store(recI + 0, w0, __ATOMIC_RELAXED, __HIP_MEMORY_SCOPE_AGENT);
        __hip_atomic_store(recI + 1, w1, __ATOMIC_RELAXED, __HIP_MEMORY_SCOPE_AGENT);
        __hip_atomic_store(recI + 2, w2, __ATOMIC_RELAXED, __HIP_MEMORY_SCOPE_AGENT);
      }
    }
    __syncthreads();  // barrier2
    cx = bc[0]; cy = bc[1]; cz = bc[2];
  }
}

extern "C" void kernel_launch(void* const* d_in, const int* in_sizes, int n_in,
                              void* d_out, int out_size, void* d_ws, size_t ws_size,
                              hipStream_t stream) {
  (void)in_sizes; (void)n_in; (void)out_size; (void)ws_size;
  const float* pts = (const float*)d_in[0];
  float* out = (float*)d_out;
  ull* ws = (ull*)d_ws;
  fps_kernel<<<dim3(NB * WPB), dim3(TPB), 0, stream>>>(pts, out, ws);
}